// Round 10
// baseline (228.897 us; speedup 1.0000x reference)
//
#include <hip/hip_runtime.h>
#include <hip/hip_bf16.h>
#include <stdint.h>

#define NB 4
#define NH 8
#define SEQ 2048
#define HD 64
#define CDIM 512

using bf16 = __hip_bfloat16;
typedef __attribute__((ext_vector_type(8))) short short8;
typedef __attribute__((ext_vector_type(4))) short short4_t;
typedef __attribute__((ext_vector_type(4))) float f32x4;

#define NEG_BIG (-3.0e38f)
#define SOFT_C 0.18033688011112042f   // log2(e)/8, folded into q at qkv epilogue

__device__ __forceinline__ short bf16_bits(float x) {
  return __builtin_bit_cast(short, __float2bfloat16(x));
}

// async global->LDS, 16B per lane; LDS dest = wave-uniform base + lane*16
__device__ __forceinline__ void gld_lds16(const void* g, void* l) {
  __builtin_amdgcn_global_load_lds(
      (const __attribute__((address_space(1))) unsigned int*)g,
      (__attribute__((address_space(3))) unsigned int*)l, 16, 0, 0);
}

// ---------------------------------------------------------------------------
// Kernel A: prep — fp32 -> bf16 for x, qkv_w, proj_w (BW-bound, ~38 MB)
// ---------------------------------------------------------------------------
#define X4 1048576   // x float4 count  (4*2048*512/4)
#define Q4 196608    // qkv_w float4 count (1536*512/4)
#define P4 65536     // proj_w float4 count (512*512/4)
__global__ __launch_bounds__(256) void prep_cvt(const float* __restrict__ x,
                                                const float* __restrict__ wq,
                                                const float* __restrict__ wp,
                                                short* __restrict__ xb,
                                                short* __restrict__ wqb,
                                                short* __restrict__ wpb) {
  int idx = blockIdx.x * 256 + threadIdx.x;
  int stride = gridDim.x * 256;
  for (int i = idx; i < X4 + Q4 + P4; i += stride) {
    const float* src; short* dst; int off;
    if (i < X4)            { src = x;  dst = xb;  off = i; }
    else if (i < X4 + Q4)  { src = wq; dst = wqb; off = i - X4; }
    else                   { src = wp; dst = wpb; off = i - X4 - Q4; }
    f32x4 v = *(const f32x4*)(src + (size_t)off * 4);
    short4_t o;
    o[0] = bf16_bits(v[0]); o[1] = bf16_bits(v[1]);
    o[2] = bf16_bits(v[2]); o[3] = bf16_bits(v[3]);
    *(short4_t*)(dst + (size_t)off * 4) = o;
  }
}

// ---------------------------------------------------------------------------
// Kernel B: union — mask pack (blocks 0..511) + QKV GEMM (512..1279).
// GEMM staged via global_load_lds (swizzled [128][32], chunk^=(row&3)).
// v col-blocks use swapped MFMA operands so vt[d][n] writes are contiguous.
// ---------------------------------------------------------------------------
__global__ __launch_bounds__(256) void qkv_union(const short* __restrict__ Xb,
                                                 const short* __restrict__ Wb,
                                                 const float* __restrict__ bias,
                                                 const int* __restrict__ mask,
                                                 unsigned long long* __restrict__ bits,
                                                 bf16* __restrict__ q,
                                                 bf16* __restrict__ k,
                                                 bf16* __restrict__ vt) {
  __shared__ short Alds[128][32];
  __shared__ short Blds[128][32];
  const int tid = threadIdx.x;
  const int lane = tid & 63;
  const int w = tid >> 6;

  if (blockIdx.x < 512) {
    int wave_g = blockIdx.x * 4 + w;
#pragma unroll 1
    for (int i = 0; i < 32; i++) {
      size_t c = (size_t)i * 2048 + wave_g;       // chunk of 256 ints, c < 65536
      size_t base = c * 256;
      int v0 = mask[base + 0 * 64 + lane];
      int v1 = mask[base + 1 * 64 + lane];
      int v2 = mask[base + 2 * 64 + lane];
      int v3 = mask[base + 3 * 64 + lane];
      unsigned long long w0 = __ballot(v0 != 0);
      unsigned long long w1 = __ballot(v1 != 0);
      unsigned long long w2 = __ballot(v2 != 0);
      unsigned long long w3 = __ballot(v3 != 0);
      if (lane == 0) {
        bits[c * 4 + 0] = w0; bits[c * 4 + 1] = w1;
        bits[c * 4 + 2] = w2; bits[c * 4 + 3] = w3;
      }
    }
    return;
  }

  const int g = blockIdx.x - 512;
  const int wm = w >> 1, wn = w & 1;
  const int row0 = (g & 63) * 128;
  const int col0 = (g >> 6) * 128;
  const bool isv = (col0 >= 1024);

  f32x4 acc[4][4] = {};
  const int cl = lane & 15;
  const int quad = lane >> 4;

  const int st_r = lane >> 2;                   // 0..15
  const int st_gc = (lane & 3) ^ (st_r & 3);    // global chunk
  const int st_col = st_gc * 8;                 // shorts
  const int fc = (quad ^ (cl & 3)) * 8;         // frag-read swizzled chunk

  for (int kk = 0; kk < 512; kk += 32) {
#pragma unroll
    for (int t = 0; t < 2; t++) {
      int R = w * 32 + t * 16;
      gld_lds16(&Xb[(size_t)(row0 + R + st_r) * 512 + kk + st_col], &Alds[R][0]);
      gld_lds16(&Wb[(size_t)(col0 + R + st_r) * 512 + kk + st_col], &Blds[R][0]);
    }
    __syncthreads();
    short8 a[4], b[4];
#pragma unroll
    for (int i = 0; i < 4; i++) a[i] = *(const short8*)&Alds[wm * 64 + i * 16 + cl][fc];
#pragma unroll
    for (int j = 0; j < 4; j++) b[j] = *(const short8*)&Blds[wn * 64 + j * 16 + cl][fc];
    if (!isv) {
#pragma unroll
      for (int i = 0; i < 4; i++)
#pragma unroll
        for (int j = 0; j < 4; j++)
          acc[i][j] = __builtin_amdgcn_mfma_f32_16x16x32_bf16(a[i], b[j], acc[i][j], 0, 0, 0);
    } else {
#pragma unroll
      for (int i = 0; i < 4; i++)
#pragma unroll
        for (int j = 0; j < 4; j++)
          acc[i][j] = __builtin_amdgcn_mfma_f32_16x16x32_bf16(b[j], a[i], acc[i][j], 0, 0, 0);
    }
    __syncthreads();
  }

  if (!isv) {
#pragma unroll
    for (int i = 0; i < 4; i++) {
#pragma unroll
      for (int j = 0; j < 4; j++) {
        int col = col0 + wn * 64 + j * 16 + cl;
        float bv = bias[col];
        int which = col >> 9;
        int c = col & 511;
        int h = c >> 6, d = c & 63;
#pragma unroll
        for (int r = 0; r < 4; r++) {
          int row = row0 + wm * 64 + i * 16 + quad * 4 + r;
          int bb = row >> 11, n = row & 2047;
          float val = acc[i][j][r] + bv;
          size_t bh = (size_t)bb * NH + h;
          if (which == 0)      q[(bh * SEQ + n) * HD + d] = __float2bfloat16(val * SOFT_C);
          else                 k[(bh * SEQ + n) * HD + d] = __float2bfloat16(val);
        }
      }
    }
  } else {
#pragma unroll
    for (int i = 0; i < 4; i++) {
#pragma unroll
      for (int j = 0; j < 4; j++) {
        int nrow = row0 + wm * 64 + i * 16 + cl;
        int bb = nrow >> 11, n = nrow & 2047;
#pragma unroll
        for (int r = 0; r < 4; r++) {
          int col = col0 + wn * 64 + j * 16 + quad * 4 + r;
          float bv = bias[col];
          int c = col & 511;
          int h = c >> 6, d = c & 63;
          float val = acc[i][j][r] + bv;
          size_t bh = (size_t)bb * NH + h;
          vt[(bh * HD + d) * SEQ + n] = __float2bfloat16(val);
        }
      }
    }
  }
}

// ---------------------------------------------------------------------------
// Kernel C: flash attention. 128 q-rows/block, 4 waves, 32 q-rows/wave in two
// 16-row groups. K/V frags read from LDS ONCE per kt into registers and
// reused by both groups (LDS-read-bound fix: 20 b128 reads per 32 MFMA).
// S^T orientation, fixed-base softmax, swizzled global_load_lds staging.
// ---------------------------------------------------------------------------
__global__ __launch_bounds__(256) void flash_attn(const bf16* __restrict__ qg,
                                                  const bf16* __restrict__ kg,
                                                  const bf16* __restrict__ vg,
                                                  const unsigned long long* __restrict__ mbits,
                                                  bf16* __restrict__ attn_out) {
  __shared__ short Klds[64][64];          // [n][d-chunk swizzled]
  __shared__ short Vlds[64][64];          // [d][n-chunk swizzled]
  __shared__ short Plds[4][16][72];       // per-wave P buffer (reused per group)
  __shared__ unsigned long long Mlds[128];

  const int tid = threadIdx.x;
  const int lane = tid & 63;
  const int w = tid >> 6;
  const int qt = blockIdx.x;              // 0..15 (128 q-rows each)
  const int h = blockIdx.y;
  const int b = blockIdx.z;

  const size_t bh = (size_t)b * NH + h;
  const bf16* qp = qg + bh * SEQ * HD;
  const bf16* kp = kg + bh * SEQ * HD;
  const bf16* vp = vg + bh * HD * SEQ;

  const int cl = lane & 15;
  const int quad = lane >> 4;
  const int koff = quad * 8;
  const int qrow_w = qt * 128 + w * 32;

  const int c0 = ((quad ^ (cl & 7)) * 8);   // swizzled frag chunk (shorts)

  const int st_row = lane >> 3;                    // 0..7 within 8-row group
  const int st_chunk = (lane & 7) ^ st_row;        // swizzled global chunk
  const int st_col = st_chunk * 8;                 // shorts

  // Q fragments for both 16-row groups (held in registers for all kt)
  short8 aq[2][2];
#pragma unroll
  for (int g = 0; g < 2; g++) {
    aq[g][0] = *(const short8*)&qp[(size_t)(qrow_w + g * 16 + cl) * HD + koff];
    aq[g][1] = *(const short8*)&qp[(size_t)(qrow_w + g * 16 + cl) * HD + 32 + koff];
  }

  f32x4 o[2][4] = {};
  float l_l[2] = {0.f, 0.f};

  for (int kt = 0; kt < 32; kt++) {
    const int kb = kt * 64;
#pragma unroll
    for (int t = 0; t < 2; t++) {
      int rbase = w * 16 + t * 8;
      gld_lds16(&kp[(size_t)(kb + rbase + st_row) * HD + st_col], &Klds[rbase][0]);
      gld_lds16(&vp[(size_t)(rbase + st_row) * SEQ + kb + st_col], &Vlds[rbase][0]);
    }
    if (tid < 128) Mlds[tid] = mbits[((size_t)b * SEQ + qt * 128 + tid) * (SEQ / 64) + kt];
    __syncthreads();

    // K and V fragments: read each LDS line exactly once, keep in regs
    short8 k0[4], k1[4], vb[2][4];
#pragma unroll
    for (int nb = 0; nb < 4; nb++) {
      k0[nb] = *(const short8*)&Klds[nb * 16 + cl][c0];
      k1[nb] = *(const short8*)&Klds[nb * 16 + cl][c0 ^ 32];
    }
#pragma unroll
    for (int ks = 0; ks < 2; ks++)
#pragma unroll
      for (int db = 0; db < 4; db++)
        vb[ks][db] = *(const short8*)&Vlds[db * 16 + cl][c0 ^ (ks * 32)];

#pragma unroll
    for (int g = 0; g < 2; g++) {
      // S^T = K·Q^T : s[nb][r] = S[qrow=cl (grp g)][kcol = nb*16 + quad*4 + r]
      f32x4 s[4];
#pragma unroll
      for (int nb = 0; nb < 4; nb++) {
        f32x4 z = {0.f, 0.f, 0.f, 0.f};
        z = __builtin_amdgcn_mfma_f32_16x16x32_bf16(k0[nb], aq[g][0], z, 0, 0, 0);
        s[nb] = __builtin_amdgcn_mfma_f32_16x16x32_bf16(k1[nb], aq[g][1], z, 0, 0, 0);
      }

      unsigned long long wd = Mlds[w * 32 + g * 16 + cl];
      if (wd != ~0ULL) {
#pragma unroll
        for (int nb = 0; nb < 4; nb++)
#pragma unroll
          for (int r = 0; r < 4; r++)
            if (!((wd >> (nb * 16 + quad * 4 + r)) & 1ULL)) s[nb][r] = NEG_BIG;
      }

      // fixed-base softmax: p = 2^s, accumulate denom
      float ps = 0.f;
#pragma unroll
      for (int nb = 0; nb < 4; nb++)
#pragma unroll
        for (int r = 0; r < 4; r++) {
          float p = __builtin_amdgcn_exp2f(s[nb][r]);
          s[nb][r] = p;
          ps += p;
        }
      ps += __shfl_xor(ps, 16);
      ps += __shfl_xor(ps, 32);
      l_l[g] += ps;

      // pack P into the per-wave buffer (intra-wave reuse across groups is
      // ordered by lgkmcnt: write->read->overwrite within one wave)
#pragma unroll
      for (int nb = 0; nb < 4; nb++) {
        short4_t pk;
        pk[0] = bf16_bits(s[nb][0]); pk[1] = bf16_bits(s[nb][1]);
        pk[2] = bf16_bits(s[nb][2]); pk[3] = bf16_bits(s[nb][3]);
        *(short4_t*)&Plds[w][cl][nb * 16 + quad * 4] = pk;
      }

      // PV: A = P (m=q-row), B = V^T (n=d) from registers
#pragma unroll
      for (int ks = 0; ks < 2; ks++) {
        short8 pa = *(const short8*)&Plds[w][cl][ks * 32 + koff];
#pragma unroll
        for (int db = 0; db < 4; db++)
          o[g][db] = __builtin_amdgcn_mfma_f32_16x16x32_bf16(pa, vb[ks][db], o[g][db], 0, 0, 0);
      }
    }
    __syncthreads();
  }

#pragma unroll
  for (int g = 0; g < 2; g++) {
    float inv = 1.0f / l_l[g];
#pragma unroll
    for (int r = 0; r < 4; r++) {
      float ir = __shfl(inv, (lane & 48) + quad * 4 + r);
      int row = qrow_w + g * 16 + quad * 4 + r;
#pragma unroll
      for (int db = 0; db < 4; db++) {
        float val = o[g][db][r] * ir;
        attn_out[((size_t)b * SEQ + row) * CDIM + h * 64 + db * 16 + cl] = __float2bfloat16(val);
      }
    }
  }
}

// ---------------------------------------------------------------------------
// Kernel D: output projection. attn[8192,512]bf16 @ Wpb[512,512]bf16^T + b
//   -> out fp32.  Staged via global_load_lds (swizzled).
// ---------------------------------------------------------------------------
__global__ __launch_bounds__(256) void proj_gemm(const bf16* __restrict__ X,
                                                 const short* __restrict__ Wb,
                                                 const float* __restrict__ bias,
                                                 float* __restrict__ out) {
  __shared__ short Alds[128][32];
  __shared__ short Blds[128][32];
  const int tid = threadIdx.x;
  const int lane = tid & 63;
  const int w = tid >> 6;
  const int wm = w >> 1, wn = w & 1;
  const int row0 = blockIdx.x * 128;
  const int col0 = blockIdx.y * 128;

  f32x4 acc[4][4] = {};
  const int cl = lane & 15;
  const int quad = lane >> 4;

  const int st_r = lane >> 2;
  const int st_gc = (lane & 3) ^ (st_r & 3);
  const int st_col = st_gc * 8;
  const int fc = (quad ^ (cl & 3)) * 8;

  for (int kk = 0; kk < 512; kk += 32) {
#pragma unroll
    for (int t = 0; t < 2; t++) {
      int R = w * 32 + t * 16;
      gld_lds16(&X[(size_t)(row0 + R + st_r) * 512 + kk + st_col], &Alds[R][0]);
      gld_lds16(&Wb[(size_t)(col0 + R + st_r) * 512 + kk + st_col], &Blds[R][0]);
    }
    __syncthreads();
    short8 a[4], b[4];
#pragma unroll
    for (int i = 0; i < 4; i++) a[i] = *(const short8*)&Alds[wm * 64 + i * 16 + cl][fc];
#pragma unroll
    for (int j = 0; j < 4; j++) b[j] = *(const short8*)&Blds[wn * 64 + j * 16 + cl][fc];
#pragma unroll
    for (int i = 0; i < 4; i++)
#pragma unroll
      for (int j = 0; j < 4; j++)
        acc[i][j] = __builtin_amdgcn_mfma_f32_16x16x32_bf16(a[i], b[j], acc[i][j], 0, 0, 0);
    __syncthreads();
  }

#pragma unroll
  for (int i = 0; i < 4; i++) {
#pragma unroll
    for (int j = 0; j < 4; j++) {
      int col = col0 + wn * 64 + j * 16 + cl;
      float bv = bias[col];
#pragma unroll
      for (int r = 0; r < 4; r++) {
        int row = row0 + wm * 64 + i * 16 + quad * 4 + r;
        out[(size_t)row * 512 + col] = acc[i][j][r] + bv;
      }
    }
  }
}

// ---------------------------------------------------------------------------
extern "C" void kernel_launch(void* const* d_in, const int* in_sizes, int n_in,
                              void* d_out, int out_size, void* d_ws, size_t ws_size,
                              hipStream_t stream) {
  const float* x      = (const float*)d_in[0];
  const float* qkv_w  = (const float*)d_in[1];
  const float* qkv_b  = (const float*)d_in[2];
  const float* proj_w = (const float*)d_in[3];
  const float* proj_b = (const float*)d_in[4];
  const int*   mask   = (const int*)d_in[5];
  float* out = (float*)d_out;

  char* ws = (char*)d_ws;
  bf16* q    = (bf16*)(ws);                 //  [0,  8 MiB)
  bf16* k    = (bf16*)(ws + 8388608);       //  [8, 16 MiB)
  bf16* vt   = (bf16*)(ws + 16777216);      //  [16,24 MiB)
  bf16* attn = (bf16*)(ws + 25165824);      //  [24,32 MiB)  (aliased with xb)
  short* xb  = (short*)(ws + 25165824);     //  xb dead before flash writes attn
  unsigned long long* mbits = (unsigned long long*)(ws + 33554432);  // [32,34 MiB)
  short* wqb = (short*)(ws + 35651584);     //  [34,35.5 MiB)
  short* wpb = (short*)(ws + 37224448);     //  [35.5,36 MiB)

  prep_cvt<<<dim3(1280), 256, 0, stream>>>(x, qkv_w, proj_w, xb, wqb, wpb);
  qkv_union<<<dim3(512 + 768), 256, 0, stream>>>(xb, wqb, qkv_b, mask, mbits, q, k, vt);
  flash_attn<<<dim3(SEQ / 128, NH, NB), 256, 0, stream>>>(q, k, vt, mbits, attn);
  proj_gemm<<<dim3(64, 4), 256, 0, stream>>>(attn, wpb, proj_b, out);
}

// Round 11
// 225.456 us; speedup vs baseline: 1.0153x; 1.0153x over previous
//
#include <hip/hip_runtime.h>
#include <hip/hip_bf16.h>
#include <stdint.h>

#define NB 4
#define NH 8
#define SEQ 2048
#define HD 64
#define CDIM 512

using bf16 = __hip_bfloat16;
typedef __attribute__((ext_vector_type(8))) short short8;
typedef __attribute__((ext_vector_type(4))) short short4_t;
typedef __attribute__((ext_vector_type(4))) float f32x4;

#define NEG_BIG (-3.0e38f)
#define SOFT_C 0.18033688011112042f   // log2(e)/8, folded into q at qkv epilogue

__device__ __forceinline__ short bf16_bits(float x) {
  return __builtin_bit_cast(short, __float2bfloat16(x));
}

// async global->LDS, 16B per lane; LDS dest = wave-uniform base + lane*16
__device__ __forceinline__ void gld_lds16(const void* g, void* l) {
  __builtin_amdgcn_global_load_lds(
      (const __attribute__((address_space(1))) unsigned int*)g,
      (__attribute__((address_space(3))) unsigned int*)l, 16, 0, 0);
}

// ---------------------------------------------------------------------------
// Kernel A: prep — fp32 -> bf16 for x, qkv_w, proj_w (BW-bound, ~38 MB)
// ---------------------------------------------------------------------------
#define X4 1048576   // x float4 count  (4*2048*512/4)
#define Q4 196608    // qkv_w float4 count (1536*512/4)
#define P4 65536     // proj_w float4 count (512*512/4)
__global__ __launch_bounds__(256) void prep_cvt(const float* __restrict__ x,
                                                const float* __restrict__ wq,
                                                const float* __restrict__ wp,
                                                short* __restrict__ xb,
                                                short* __restrict__ wqb,
                                                short* __restrict__ wpb) {
  int idx = blockIdx.x * 256 + threadIdx.x;
  int stride = gridDim.x * 256;
  for (int i = idx; i < X4 + Q4 + P4; i += stride) {
    const float* src; short* dst; int off;
    if (i < X4)            { src = x;  dst = xb;  off = i; }
    else if (i < X4 + Q4)  { src = wq; dst = wqb; off = i - X4; }
    else                   { src = wp; dst = wpb; off = i - X4 - Q4; }
    f32x4 v = *(const f32x4*)(src + (size_t)off * 4);
    short4_t o;
    o[0] = bf16_bits(v[0]); o[1] = bf16_bits(v[1]);
    o[2] = bf16_bits(v[2]); o[3] = bf16_bits(v[3]);
    *(short4_t*)(dst + (size_t)off * 4) = o;
  }
}

// ---------------------------------------------------------------------------
// Kernel B: union — mask pack (blocks 0..511) + QKV GEMM (512..1279).
// GEMM staged via global_load_lds (swizzled [128][32], chunk^=(row&3)).
// v col-blocks use swapped MFMA operands so vt[d][n] writes are contiguous.
// ---------------------------------------------------------------------------
__global__ __launch_bounds__(256) void qkv_union(const short* __restrict__ Xb,
                                                 const short* __restrict__ Wb,
                                                 const float* __restrict__ bias,
                                                 const int* __restrict__ mask,
                                                 unsigned long long* __restrict__ bits,
                                                 bf16* __restrict__ q,
                                                 bf16* __restrict__ k,
                                                 bf16* __restrict__ vt) {
  __shared__ short Alds[128][32];
  __shared__ short Blds[128][32];
  const int tid = threadIdx.x;
  const int lane = tid & 63;
  const int w = tid >> 6;

  if (blockIdx.x < 512) {
    int wave_g = blockIdx.x * 4 + w;
#pragma unroll 1
    for (int i = 0; i < 32; i++) {
      size_t c = (size_t)i * 2048 + wave_g;       // chunk of 256 ints, c < 65536
      size_t base = c * 256;
      int v0 = mask[base + 0 * 64 + lane];
      int v1 = mask[base + 1 * 64 + lane];
      int v2 = mask[base + 2 * 64 + lane];
      int v3 = mask[base + 3 * 64 + lane];
      unsigned long long w0 = __ballot(v0 != 0);
      unsigned long long w1 = __ballot(v1 != 0);
      unsigned long long w2 = __ballot(v2 != 0);
      unsigned long long w3 = __ballot(v3 != 0);
      if (lane == 0) {
        bits[c * 4 + 0] = w0; bits[c * 4 + 1] = w1;
        bits[c * 4 + 2] = w2; bits[c * 4 + 3] = w3;
      }
    }
    return;
  }

  const int g = blockIdx.x - 512;
  const int wm = w >> 1, wn = w & 1;
  const int row0 = (g & 63) * 128;
  const int col0 = (g >> 6) * 128;
  const bool isv = (col0 >= 1024);

  f32x4 acc[4][4] = {};
  const int cl = lane & 15;
  const int quad = lane >> 4;

  const int st_r = lane >> 2;                   // 0..15
  const int st_gc = (lane & 3) ^ (st_r & 3);    // global chunk
  const int st_col = st_gc * 8;                 // shorts
  const int fc = (quad ^ (cl & 3)) * 8;         // frag-read swizzled chunk

  for (int kk = 0; kk < 512; kk += 32) {
#pragma unroll
    for (int t = 0; t < 2; t++) {
      int R = w * 32 + t * 16;
      gld_lds16(&Xb[(size_t)(row0 + R + st_r) * 512 + kk + st_col], &Alds[R][0]);
      gld_lds16(&Wb[(size_t)(col0 + R + st_r) * 512 + kk + st_col], &Blds[R][0]);
    }
    __syncthreads();
    short8 a[4], b[4];
#pragma unroll
    for (int i = 0; i < 4; i++) a[i] = *(const short8*)&Alds[wm * 64 + i * 16 + cl][fc];
#pragma unroll
    for (int j = 0; j < 4; j++) b[j] = *(const short8*)&Blds[wn * 64 + j * 16 + cl][fc];
    if (!isv) {
#pragma unroll
      for (int i = 0; i < 4; i++)
#pragma unroll
        for (int j = 0; j < 4; j++)
          acc[i][j] = __builtin_amdgcn_mfma_f32_16x16x32_bf16(a[i], b[j], acc[i][j], 0, 0, 0);
    } else {
#pragma unroll
      for (int i = 0; i < 4; i++)
#pragma unroll
        for (int j = 0; j < 4; j++)
          acc[i][j] = __builtin_amdgcn_mfma_f32_16x16x32_bf16(b[j], a[i], acc[i][j], 0, 0, 0);
    }
    __syncthreads();
  }

  if (!isv) {
#pragma unroll
    for (int i = 0; i < 4; i++) {
#pragma unroll
      for (int j = 0; j < 4; j++) {
        int col = col0 + wn * 64 + j * 16 + cl;
        float bv = bias[col];
        int which = col >> 9;
        int c = col & 511;
        int h = c >> 6, d = c & 63;
#pragma unroll
        for (int r = 0; r < 4; r++) {
          int row = row0 + wm * 64 + i * 16 + quad * 4 + r;
          int bb = row >> 11, n = row & 2047;
          float val = acc[i][j][r] + bv;
          size_t bh = (size_t)bb * NH + h;
          if (which == 0)      q[(bh * SEQ + n) * HD + d] = __float2bfloat16(val * SOFT_C);
          else                 k[(bh * SEQ + n) * HD + d] = __float2bfloat16(val);
        }
      }
    }
  } else {
#pragma unroll
    for (int i = 0; i < 4; i++) {
#pragma unroll
      for (int j = 0; j < 4; j++) {
        int nrow = row0 + wm * 64 + i * 16 + cl;
        int bb = nrow >> 11, n = nrow & 2047;
#pragma unroll
        for (int r = 0; r < 4; r++) {
          int col = col0 + wn * 64 + j * 16 + quad * 4 + r;
          float bv = bias[col];
          int c = col & 511;
          int h = c >> 6, d = c & 63;
          float val = acc[i][j][r] + bv;
          size_t bh = (size_t)bb * NH + h;
          vt[(bh * HD + d) * SEQ + n] = __float2bfloat16(val);
        }
      }
    }
  }
}

// ---------------------------------------------------------------------------
// Kernel C: flash attention. 128 q-rows/block, 32 q-rows/wave (2 groups).
// Double-buffered K/V staging (1 barrier/kt, loads land during compute);
// per-group P buffers (no WAR serialization); group phases batched for ILP.
// ---------------------------------------------------------------------------
__global__ __launch_bounds__(256) void flash_attn(const bf16* __restrict__ qg,
                                                  const bf16* __restrict__ kg,
                                                  const bf16* __restrict__ vg,
                                                  const unsigned long long* __restrict__ mbits,
                                                  bf16* __restrict__ attn_out) {
  __shared__ short Klds[2][64][64];       // [buf][n][d-chunk swizzled]
  __shared__ short Vlds[2][64][64];       // [buf][d][n-chunk swizzled]
  __shared__ short Plds[4][2][16][72];    // per-wave, PER-GROUP P buffers
  __shared__ unsigned long long Mlds[2][128];

  const int tid = threadIdx.x;
  const int lane = tid & 63;
  const int w = tid >> 6;
  const int qt = blockIdx.x;              // 0..15 (128 q-rows each)
  const int h = blockIdx.y;
  const int b = blockIdx.z;

  const size_t bh = (size_t)b * NH + h;
  const bf16* qp = qg + bh * SEQ * HD;
  const bf16* kp = kg + bh * SEQ * HD;
  const bf16* vp = vg + bh * HD * SEQ;

  const int cl = lane & 15;
  const int quad = lane >> 4;
  const int koff = quad * 8;
  const int qrow_w = qt * 128 + w * 32;

  const int c0 = ((quad ^ (cl & 7)) * 8);   // swizzled frag chunk (shorts)

  const int st_row = lane >> 3;                    // 0..7 within 8-row group
  const int st_chunk = (lane & 7) ^ st_row;        // swizzled global chunk
  const int st_col = st_chunk * 8;                 // shorts

  // Q fragments for both 16-row groups (registers, all kt)
  short8 aq[2][2];
#pragma unroll
  for (int g = 0; g < 2; g++) {
    aq[g][0] = *(const short8*)&qp[(size_t)(qrow_w + g * 16 + cl) * HD + koff];
    aq[g][1] = *(const short8*)&qp[(size_t)(qrow_w + g * 16 + cl) * HD + 32 + koff];
  }

  f32x4 o[2][4] = {};
  float l_l[2] = {0.f, 0.f};

  // prologue: stage kt=0 into buf 0
#pragma unroll
  for (int t = 0; t < 2; t++) {
    int rbase = w * 16 + t * 8;
    gld_lds16(&kp[(size_t)(rbase + st_row) * HD + st_col], &Klds[0][rbase][0]);
    gld_lds16(&vp[(size_t)(rbase + st_row) * SEQ + st_col], &Vlds[0][rbase][0]);
  }
  if (tid < 128) Mlds[0][tid] = mbits[((size_t)b * SEQ + qt * 128 + tid) * (SEQ / 64) + 0];

  for (int kt = 0; kt < 32; kt++) {
    const int cur = kt & 1;
    __syncthreads();   // buf cur staged; buf cur^1 free (prev compute done)

    // stage kt+1 into buf cur^1 (lands during this kt's compute)
    if (kt + 1 < 32) {
      const int kb2 = (kt + 1) * 64;
#pragma unroll
      for (int t = 0; t < 2; t++) {
        int rbase = w * 16 + t * 8;
        gld_lds16(&kp[(size_t)(kb2 + rbase + st_row) * HD + st_col], &Klds[cur ^ 1][rbase][0]);
        gld_lds16(&vp[(size_t)(rbase + st_row) * SEQ + kb2 + st_col], &Vlds[cur ^ 1][rbase][0]);
      }
      if (tid < 128)
        Mlds[cur ^ 1][tid] = mbits[((size_t)b * SEQ + qt * 128 + tid) * (SEQ / 64) + kt + 1];
    }

    // K/V fragments: read each LDS line once, keep in regs
    short8 k0[4], k1[4], vb[2][4];
#pragma unroll
    for (int nb = 0; nb < 4; nb++) {
      k0[nb] = *(const short8*)&Klds[cur][nb * 16 + cl][c0];
      k1[nb] = *(const short8*)&Klds[cur][nb * 16 + cl][c0 ^ 32];
    }
#pragma unroll
    for (int ks = 0; ks < 2; ks++)
#pragma unroll
      for (int db = 0; db < 4; db++)
        vb[ks][db] = *(const short8*)&Vlds[cur][db * 16 + cl][c0 ^ (ks * 32)];

    // phase 1: S^T for BOTH groups (independent MFMA chains)
    f32x4 s[2][4];
#pragma unroll
    for (int g = 0; g < 2; g++)
#pragma unroll
      for (int nb = 0; nb < 4; nb++) {
        f32x4 z = {0.f, 0.f, 0.f, 0.f};
        z = __builtin_amdgcn_mfma_f32_16x16x32_bf16(k0[nb], aq[g][0], z, 0, 0, 0);
        s[g][nb] = __builtin_amdgcn_mfma_f32_16x16x32_bf16(k1[nb], aq[g][1], z, 0, 0, 0);
      }

    // phase 2: mask + fixed-base softmax + pack, both groups
#pragma unroll
    for (int g = 0; g < 2; g++) {
      unsigned long long wd = Mlds[cur][w * 32 + g * 16 + cl];
      if (wd != ~0ULL) {
#pragma unroll
        for (int nb = 0; nb < 4; nb++)
#pragma unroll
          for (int r = 0; r < 4; r++)
            if (!((wd >> (nb * 16 + quad * 4 + r)) & 1ULL)) s[g][nb][r] = NEG_BIG;
      }
      float ps = 0.f;
#pragma unroll
      for (int nb = 0; nb < 4; nb++)
#pragma unroll
        for (int r = 0; r < 4; r++) {
          float p = __builtin_amdgcn_exp2f(s[g][nb][r]);
          s[g][nb][r] = p;
          ps += p;
        }
      ps += __shfl_xor(ps, 16);
      ps += __shfl_xor(ps, 32);
      l_l[g] += ps;
#pragma unroll
      for (int nb = 0; nb < 4; nb++) {
        short4_t pk;
        pk[0] = bf16_bits(s[g][nb][0]); pk[1] = bf16_bits(s[g][nb][1]);
        pk[2] = bf16_bits(s[g][nb][2]); pk[3] = bf16_bits(s[g][nb][3]);
        *(short4_t*)&Plds[w][g][cl][nb * 16 + quad * 4] = pk;
      }
    }

    // phase 3: PV for both groups
#pragma unroll
    for (int g = 0; g < 2; g++)
#pragma unroll
      for (int ks = 0; ks < 2; ks++) {
        short8 pa = *(const short8*)&Plds[w][g][cl][ks * 32 + koff];
#pragma unroll
        for (int db = 0; db < 4; db++)
          o[g][db] = __builtin_amdgcn_mfma_f32_16x16x32_bf16(pa, vb[ks][db], o[g][db], 0, 0, 0);
      }
  }

#pragma unroll
  for (int g = 0; g < 2; g++) {
    float inv = 1.0f / l_l[g];
#pragma unroll
    for (int r = 0; r < 4; r++) {
      float ir = __shfl(inv, (lane & 48) + quad * 4 + r);
      int row = qrow_w + g * 16 + quad * 4 + r;
#pragma unroll
      for (int db = 0; db < 4; db++) {
        float val = o[g][db][r] * ir;
        attn_out[((size_t)b * SEQ + row) * CDIM + h * 64 + db * 16 + cl] = __float2bfloat16(val);
      }
    }
  }
}

// ---------------------------------------------------------------------------
// Kernel D: output projection. attn[8192,512]bf16 @ Wpb[512,512]bf16^T + b
//   -> out fp32.  Staged via global_load_lds (swizzled).
// ---------------------------------------------------------------------------
__global__ __launch_bounds__(256) void proj_gemm(const bf16* __restrict__ X,
                                                 const short* __restrict__ Wb,
                                                 const float* __restrict__ bias,
                                                 float* __restrict__ out) {
  __shared__ short Alds[128][32];
  __shared__ short Blds[128][32];
  const int tid = threadIdx.x;
  const int lane = tid & 63;
  const int w = tid >> 6;
  const int wm = w >> 1, wn = w & 1;
  const int row0 = blockIdx.x * 128;
  const int col0 = blockIdx.y * 128;

  f32x4 acc[4][4] = {};
  const int cl = lane & 15;
  const int quad = lane >> 4;

  const int st_r = lane >> 2;
  const int st_gc = (lane & 3) ^ (st_r & 3);
  const int st_col = st_gc * 8;
  const int fc = (quad ^ (cl & 3)) * 8;

  for (int kk = 0; kk < 512; kk += 32) {
#pragma unroll
    for (int t = 0; t < 2; t++) {
      int R = w * 32 + t * 16;
      gld_lds16(&X[(size_t)(row0 + R + st_r) * 512 + kk + st_col], &Alds[R][0]);
      gld_lds16(&Wb[(size_t)(col0 + R + st_r) * 512 + kk + st_col], &Blds[R][0]);
    }
    __syncthreads();
    short8 a[4], b[4];
#pragma unroll
    for (int i = 0; i < 4; i++) a[i] = *(const short8*)&Alds[wm * 64 + i * 16 + cl][fc];
#pragma unroll
    for (int j = 0; j < 4; j++) b[j] = *(const short8*)&Blds[wn * 64 + j * 16 + cl][fc];
#pragma unroll
    for (int i = 0; i < 4; i++)
#pragma unroll
      for (int j = 0; j < 4; j++)
        acc[i][j] = __builtin_amdgcn_mfma_f32_16x16x32_bf16(a[i], b[j], acc[i][j], 0, 0, 0);
    __syncthreads();
  }

#pragma unroll
  for (int i = 0; i < 4; i++) {
#pragma unroll
    for (int j = 0; j < 4; j++) {
      int col = col0 + wn * 64 + j * 16 + cl;
      float bv = bias[col];
#pragma unroll
      for (int r = 0; r < 4; r++) {
        int row = row0 + wm * 64 + i * 16 + quad * 4 + r;
        out[(size_t)row * 512 + col] = acc[i][j][r] + bv;
      }
    }
  }
}

// ---------------------------------------------------------------------------
extern "C" void kernel_launch(void* const* d_in, const int* in_sizes, int n_in,
                              void* d_out, int out_size, void* d_ws, size_t ws_size,
                              hipStream_t stream) {
  const float* x      = (const float*)d_in[0];
  const float* qkv_w  = (const float*)d_in[1];
  const float* qkv_b  = (const float*)d_in[2];
  const float* proj_w = (const float*)d_in[3];
  const float* proj_b = (const float*)d_in[4];
  const int*   mask   = (const int*)d_in[5];
  float* out = (float*)d_out;

  char* ws = (char*)d_ws;
  bf16* q    = (bf16*)(ws);                 //  [0,  8 MiB)
  bf16* k    = (bf16*)(ws + 8388608);       //  [8, 16 MiB)
  bf16* vt   = (bf16*)(ws + 16777216);      //  [16,24 MiB)
  bf16* attn = (bf16*)(ws + 25165824);      //  [24,32 MiB)  (aliased with xb)
  short* xb  = (short*)(ws + 25165824);     //  xb dead before flash writes attn
  unsigned long long* mbits = (unsigned long long*)(ws + 33554432);  // [32,34 MiB)
  short* wqb = (short*)(ws + 35651584);     //  [34,35.5 MiB)
  short* wpb = (short*)(ws + 37224448);     //  [35.5,36 MiB)

  prep_cvt<<<dim3(1280), 256, 0, stream>>>(x, qkv_w, proj_w, xb, wqb, wpb);
  qkv_union<<<dim3(512 + 768), 256, 0, stream>>>(xb, wqb, qkv_b, mask, mbits, q, k, vt);
  flash_attn<<<dim3(SEQ / 128, NH, NB), 256, 0, stream>>>(q, k, vt, mbits, attn);
  proj_gemm<<<dim3(64, 4), 256, 0, stream>>>(attn, wpb, proj_b, out);
}

// Round 13
// 222.078 us; speedup vs baseline: 1.0307x; 1.0152x over previous
//
#include <hip/hip_runtime.h>
#include <hip/hip_bf16.h>
#include <stdint.h>

#define NB 4
#define NH 8
#define SEQ 2048
#define HD 64
#define CDIM 512

using bf16 = __hip_bfloat16;
typedef __attribute__((ext_vector_type(8))) short short8;
typedef __attribute__((ext_vector_type(4))) short short4_t;
typedef __attribute__((ext_vector_type(2))) unsigned int uint2_t;
typedef __attribute__((ext_vector_type(4))) float f32x4;

#define NEG_BIG (-3.0e38f)
#define SOFT_C 0.18033688011112042f   // log2(e)/8, folded into q at qkv epilogue

__device__ __forceinline__ short bf16_bits(float x) {
  return __builtin_bit_cast(short, __float2bfloat16(x));
}

// pack 4 fp32 -> 4 bf16 bits (8B) and store to LDS as one b64
__device__ __forceinline__ void pack_p4(float a, float b, float c, float d, short* dst) {
  unsigned lo = (unsigned)(unsigned short)bf16_bits(a) |
                ((unsigned)(unsigned short)bf16_bits(b) << 16);
  unsigned hi = (unsigned)(unsigned short)bf16_bits(c) |
                ((unsigned)(unsigned short)bf16_bits(d) << 16);
  uint2_t t;
  t[0] = lo;
  t[1] = hi;
  *(uint2_t*)dst = t;
}

// async global->LDS, 16B per lane; LDS dest = wave-uniform base + lane*16
__device__ __forceinline__ void gld_lds16(const void* g, void* l) {
  __builtin_amdgcn_global_load_lds(
      (const __attribute__((address_space(1))) unsigned int*)g,
      (__attribute__((address_space(3))) unsigned int*)l, 16, 0, 0);
}

// ---------------------------------------------------------------------------
// Kernel A: prep — fp32 -> bf16 for x, qkv_w, proj_w (BW-bound, ~38 MB)
// ---------------------------------------------------------------------------
#define X4 1048576   // x float4 count  (4*2048*512/4)
#define Q4 196608    // qkv_w float4 count (1536*512/4)
#define P4 65536     // proj_w float4 count (512*512/4)
__global__ __launch_bounds__(256) void prep_cvt(const float* __restrict__ x,
                                                const float* __restrict__ wq,
                                                const float* __restrict__ wp,
                                                short* __restrict__ xb,
                                                short* __restrict__ wqb,
                                                short* __restrict__ wpb) {
  int idx = blockIdx.x * 256 + threadIdx.x;
  int stride = gridDim.x * 256;
  for (int i = idx; i < X4 + Q4 + P4; i += stride) {
    const float* src; short* dst; int off;
    if (i < X4)            { src = x;  dst = xb;  off = i; }
    else if (i < X4 + Q4)  { src = wq; dst = wqb; off = i - X4; }
    else                   { src = wp; dst = wpb; off = i - X4 - Q4; }
    f32x4 v = *(const f32x4*)(src + (size_t)off * 4);
    short4_t o;
    o[0] = bf16_bits(v[0]); o[1] = bf16_bits(v[1]);
    o[2] = bf16_bits(v[2]); o[3] = bf16_bits(v[3]);
    *(short4_t*)(dst + (size_t)off * 4) = o;
  }
}

// ---------------------------------------------------------------------------
// Kernel B: union — mask pack (blocks 0..511) + QKV GEMM (512..1279).
// GEMM staged via global_load_lds (swizzled [128][32], chunk^=(row&3)).
// v col-blocks use swapped MFMA operands so vt[d][n] writes are contiguous.
// ---------------------------------------------------------------------------
__global__ __launch_bounds__(256) void qkv_union(const short* __restrict__ Xb,
                                                 const short* __restrict__ Wb,
                                                 const float* __restrict__ bias,
                                                 const int* __restrict__ mask,
                                                 unsigned long long* __restrict__ bits,
                                                 bf16* __restrict__ q,
                                                 bf16* __restrict__ k,
                                                 bf16* __restrict__ vt) {
  __shared__ short Alds[128][32];
  __shared__ short Blds[128][32];
  const int tid = threadIdx.x;
  const int lane = tid & 63;
  const int w = tid >> 6;

  if (blockIdx.x < 512) {
    int wave_g = blockIdx.x * 4 + w;
#pragma unroll 1
    for (int i = 0; i < 32; i++) {
      size_t c = (size_t)i * 2048 + wave_g;       // chunk of 256 ints, c < 65536
      size_t base = c * 256;
      int v0 = mask[base + 0 * 64 + lane];
      int v1 = mask[base + 1 * 64 + lane];
      int v2 = mask[base + 2 * 64 + lane];
      int v3 = mask[base + 3 * 64 + lane];
      unsigned long long w0 = __ballot(v0 != 0);
      unsigned long long w1 = __ballot(v1 != 0);
      unsigned long long w2 = __ballot(v2 != 0);
      unsigned long long w3 = __ballot(v3 != 0);
      if (lane == 0) {
        bits[c * 4 + 0] = w0; bits[c * 4 + 1] = w1;
        bits[c * 4 + 2] = w2; bits[c * 4 + 3] = w3;
      }
    }
    return;
  }

  const int g = blockIdx.x - 512;
  const int wm = w >> 1, wn = w & 1;
  const int row0 = (g & 63) * 128;
  const int col0 = (g >> 6) * 128;
  const bool isv = (col0 >= 1024);

  f32x4 acc[4][4] = {};
  const int cl = lane & 15;
  const int quad = lane >> 4;

  const int st_r = lane >> 2;                   // 0..15
  const int st_gc = (lane & 3) ^ (st_r & 3);    // global chunk
  const int st_col = st_gc * 8;                 // shorts
  const int fc = (quad ^ (cl & 3)) * 8;         // frag-read swizzled chunk

  for (int kk = 0; kk < 512; kk += 32) {
#pragma unroll
    for (int t = 0; t < 2; t++) {
      int R = w * 32 + t * 16;
      gld_lds16(&Xb[(size_t)(row0 + R + st_r) * 512 + kk + st_col], &Alds[R][0]);
      gld_lds16(&Wb[(size_t)(col0 + R + st_r) * 512 + kk + st_col], &Blds[R][0]);
    }
    __syncthreads();
    short8 a[4], b[4];
#pragma unroll
    for (int i = 0; i < 4; i++) a[i] = *(const short8*)&Alds[wm * 64 + i * 16 + cl][fc];
#pragma unroll
    for (int j = 0; j < 4; j++) b[j] = *(const short8*)&Blds[wn * 64 + j * 16 + cl][fc];
    if (!isv) {
#pragma unroll
      for (int i = 0; i < 4; i++)
#pragma unroll
        for (int j = 0; j < 4; j++)
          acc[i][j] = __builtin_amdgcn_mfma_f32_16x16x32_bf16(a[i], b[j], acc[i][j], 0, 0, 0);
    } else {
#pragma unroll
      for (int i = 0; i < 4; i++)
#pragma unroll
        for (int j = 0; j < 4; j++)
          acc[i][j] = __builtin_amdgcn_mfma_f32_16x16x32_bf16(b[j], a[i], acc[i][j], 0, 0, 0);
    }
    __syncthreads();
  }

  if (!isv) {
#pragma unroll
    for (int i = 0; i < 4; i++) {
#pragma unroll
      for (int j = 0; j < 4; j++) {
        int col = col0 + wn * 64 + j * 16 + cl;
        float bv = bias[col];
        int which = col >> 9;
        int c = col & 511;
        int h = c >> 6, d = c & 63;
#pragma unroll
        for (int r = 0; r < 4; r++) {
          int row = row0 + wm * 64 + i * 16 + quad * 4 + r;
          int bb = row >> 11, n = row & 2047;
          float val = acc[i][j][r] + bv;
          size_t bh = (size_t)bb * NH + h;
          if (which == 0)      q[(bh * SEQ + n) * HD + d] = __float2bfloat16(val * SOFT_C);
          else                 k[(bh * SEQ + n) * HD + d] = __float2bfloat16(val);
        }
      }
    }
  } else {
#pragma unroll
    for (int i = 0; i < 4; i++) {
#pragma unroll
      for (int j = 0; j < 4; j++) {
        int nrow = row0 + wm * 64 + i * 16 + cl;
        int bb = nrow >> 11, n = nrow & 2047;
#pragma unroll
        for (int r = 0; r < 4; r++) {
          int col = col0 + wn * 64 + j * 16 + quad * 4 + r;
          float bv = bias[col];
          int c = col & 511;
          int h = c >> 6, d = c & 63;
          float val = acc[i][j][r] + bv;
          size_t bh = (size_t)bb * NH + h;
          vt[(bh * HD + d) * SEQ + n] = __float2bfloat16(val);
        }
      }
    }
  }
}

// ---------------------------------------------------------------------------
// Kernel C: flash attention. 128 q-rows/block, 32 q-rows/wave (2 groups).
// Double-buffered K/V via global_load_lds. Mask words prefetched into
// REGISTERS one kt ahead (no LDS roundtrip, no mid-loop vmcnt(0) stall).
// Denominator folded into an extra ones-column PV MFMA (no adds/shuffles).
// ---------------------------------------------------------------------------
__global__ __launch_bounds__(256) void flash_attn(const bf16* __restrict__ qg,
                                                  const bf16* __restrict__ kg,
                                                  const bf16* __restrict__ vg,
                                                  const unsigned long long* __restrict__ mbits,
                                                  bf16* __restrict__ attn_out) {
  __shared__ short Klds[2][64][64];       // [buf][n][d-chunk swizzled]
  __shared__ short Vlds[2][64][64];       // [buf][d][n-chunk swizzled]
  __shared__ short Plds[4][2][16][72];    // per-wave, per-group P buffers

  const int tid = threadIdx.x;
  const int lane = tid & 63;
  const int w = tid >> 6;
  const int qt = blockIdx.x;              // 0..15 (128 q-rows each)
  const int h = blockIdx.y;
  const int b = blockIdx.z;

  const size_t bh = (size_t)b * NH + h;
  const bf16* qp = qg + bh * SEQ * HD;
  const bf16* kp = kg + bh * SEQ * HD;
  const bf16* vp = vg + bh * HD * SEQ;

  const int cl = lane & 15;
  const int quad = lane >> 4;
  const int koff = quad * 8;
  const int qrow_w = qt * 128 + w * 32;

  const int c0 = ((quad ^ (cl & 7)) * 8);   // swizzled frag chunk (shorts)

  const int st_row = lane >> 3;                    // 0..7 within 8-row group
  const int st_chunk = (lane & 7) ^ st_row;        // swizzled global chunk
  const int st_col = st_chunk * 8;                 // shorts

  // per-lane mask row pointers (32 words per row)
  const unsigned long long* mr0 = mbits + ((size_t)b * SEQ + qt * 128 + w * 32 + cl) * 32;
  const unsigned long long* mr1 = mr0 + 16 * 32;

  // Q fragments for both 16-row groups (registers, all kt)
  short8 aq[2][2];
#pragma unroll
  for (int g = 0; g < 2; g++) {
    aq[g][0] = *(const short8*)&qp[(size_t)(qrow_w + g * 16 + cl) * HD + koff];
    aq[g][1] = *(const short8*)&qp[(size_t)(qrow_w + g * 16 + cl) * HD + 32 + koff];
  }

  // ones fragment for denominator column
  short8 ones;
#pragma unroll
  for (int i = 0; i < 8; i++) ones[i] = (short)0x3F80;

  f32x4 o[2][4] = {};
  f32x4 ol[2] = {};   // row-sum accumulators (denominator), C-layout rows

  // prologue: stage kt=0 into buf 0; prefetch kt=0 mask words
#pragma unroll
  for (int t = 0; t < 2; t++) {
    int rbase = w * 16 + t * 8;
    gld_lds16(&kp[(size_t)(rbase + st_row) * HD + st_col], &Klds[0][rbase][0]);
    gld_lds16(&vp[(size_t)(rbase + st_row) * SEQ + st_col], &Vlds[0][rbase][0]);
  }
  unsigned long long wd_next[2];
  wd_next[0] = mr0[0];
  wd_next[1] = mr1[0];
  __syncthreads();   // drains vmcnt: buf 0 landed for all waves

  for (int kt = 0; kt < 32; kt++) {
    const int cur = kt & 1;

    // K/V fragments: read each LDS line once, keep in regs
    short8 k0[4], k1[4], vb[2][4];
#pragma unroll
    for (int nb = 0; nb < 4; nb++) {
      k0[nb] = *(const short8*)&Klds[cur][nb * 16 + cl][c0];
      k1[nb] = *(const short8*)&Klds[cur][nb * 16 + cl][c0 ^ 32];
    }
#pragma unroll
    for (int ks = 0; ks < 2; ks++)
#pragma unroll
      for (int db = 0; db < 4; db++)
        vb[ks][db] = *(const short8*)&Vlds[cur][db * 16 + cl][c0 ^ (ks * 32)];

    // issue next staging + mask prefetch (land during this kt's compute)
    if (kt + 1 < 32) {
      const int kb2 = (kt + 1) * 64;
#pragma unroll
      for (int t = 0; t < 2; t++) {
        int rbase = w * 16 + t * 8;
        gld_lds16(&kp[(size_t)(kb2 + rbase + st_row) * HD + st_col], &Klds[cur ^ 1][rbase][0]);
        gld_lds16(&vp[(size_t)(rbase + st_row) * SEQ + kb2 + st_col], &Vlds[cur ^ 1][rbase][0]);
      }
    }
    unsigned long long wd[2] = {wd_next[0], wd_next[1]};
    if (kt + 1 < 32) {
      wd_next[0] = mr0[kt + 1];
      wd_next[1] = mr1[kt + 1];
    }

    // phase 1: S^T for BOTH groups (independent MFMA chains)
    f32x4 s[2][4];
#pragma unroll
    for (int g = 0; g < 2; g++)
#pragma unroll
      for (int nb = 0; nb < 4; nb++) {
        f32x4 z = {0.f, 0.f, 0.f, 0.f};
        z = __builtin_amdgcn_mfma_f32_16x16x32_bf16(k0[nb], aq[g][0], z, 0, 0, 0);
        s[g][nb] = __builtin_amdgcn_mfma_f32_16x16x32_bf16(k1[nb], aq[g][1], z, 0, 0, 0);
      }

    // phase 2: mask + fixed-base exp2 + packed P write
#pragma unroll
    for (int g = 0; g < 2; g++) {
      if (wd[g] != ~0ULL) {
#pragma unroll
        for (int nb = 0; nb < 4; nb++)
#pragma unroll
          for (int r = 0; r < 4; r++)
            if (!((wd[g] >> (nb * 16 + quad * 4 + r)) & 1ULL)) s[g][nb][r] = NEG_BIG;
      }
#pragma unroll
      for (int nb = 0; nb < 4; nb++) {
#pragma unroll
        for (int r = 0; r < 4; r++) s[g][nb][r] = __builtin_amdgcn_exp2f(s[g][nb][r]);
        pack_p4(s[g][nb][0], s[g][nb][1], s[g][nb][2], s[g][nb][3],
                &Plds[w][g][cl][nb * 16 + quad * 4]);
      }
    }

    // phase 3: PV + ones-column denominator
#pragma unroll
    for (int g = 0; g < 2; g++)
#pragma unroll
      for (int ks = 0; ks < 2; ks++) {
        short8 pa = *(const short8*)&Plds[w][g][cl][ks * 32 + koff];
#pragma unroll
        for (int db = 0; db < 4; db++)
          o[g][db] = __builtin_amdgcn_mfma_f32_16x16x32_bf16(pa, vb[ks][db], o[g][db], 0, 0, 0);
        ol[g] = __builtin_amdgcn_mfma_f32_16x16x32_bf16(pa, ones, ol[g], 0, 0, 0);
      }

    __syncthreads();   // next buf landed (loads issued ~1 compute phase ago)
  }

  // epilogue: denominators already per-lane in C-layout rows — no shuffles
#pragma unroll
  for (int g = 0; g < 2; g++) {
#pragma unroll
    for (int r = 0; r < 4; r++) {
      float inv = 1.0f / ol[g][r];
      int row = qrow_w + g * 16 + quad * 4 + r;
#pragma unroll
      for (int db = 0; db < 4; db++) {
        float val = o[g][db][r] * inv;
        attn_out[((size_t)b * SEQ + row) * CDIM + h * 64 + db * 16 + cl] = __float2bfloat16(val);
      }
    }
  }
}

// ---------------------------------------------------------------------------
// Kernel D: output projection. attn[8192,512]bf16 @ Wpb[512,512]bf16^T + b
//   -> out fp32.  Staged via global_load_lds (swizzled).
// ---------------------------------------------------------------------------
__global__ __launch_bounds__(256) void proj_gemm(const bf16* __restrict__ X,
                                                 const short* __restrict__ Wb,
                                                 const float* __restrict__ bias,
                                                 float* __restrict__ out) {
  __shared__ short Alds[128][32];
  __shared__ short Blds[128][32];
  const int tid = threadIdx.x;
  const int lane = tid & 63;
  const int w = tid >> 6;
  const int wm = w >> 1, wn = w & 1;
  const int row0 = blockIdx.x * 128;
  const int col0 = blockIdx.y * 128;

  f32x4 acc[4][4] = {};
  const int cl = lane & 15;
  const int quad = lane >> 4;

  const int st_r = lane >> 2;
  const int st_gc = (lane & 3) ^ (st_r & 3);
  const int st_col = st_gc * 8;
  const int fc = (quad ^ (cl & 3)) * 8;

  for (int kk = 0; kk < 512; kk += 32) {
#pragma unroll
    for (int t = 0; t < 2; t++) {
      int R = w * 32 + t * 16;
      gld_lds16(&X[(size_t)(row0 + R + st_r) * 512 + kk + st_col], &Alds[R][0]);
      gld_lds16(&Wb[(size_t)(col0 + R + st_r) * 512 + kk + st_col], &Blds[R][0]);
    }
    __syncthreads();
    short8 a[4], b[4];
#pragma unroll
    for (int i = 0; i < 4; i++) a[i] = *(const short8*)&Alds[wm * 64 + i * 16 + cl][fc];
#pragma unroll
    for (int j = 0; j < 4; j++) b[j] = *(const short8*)&Blds[wn * 64 + j * 16 + cl][fc];
#pragma unroll
    for (int i = 0; i < 4; i++)
#pragma unroll
      for (int j = 0; j < 4; j++)
        acc[i][j] = __builtin_amdgcn_mfma_f32_16x16x32_bf16(a[i], b[j], acc[i][j], 0, 0, 0);
    __syncthreads();
  }

#pragma unroll
  for (int i = 0; i < 4; i++) {
#pragma unroll
    for (int j = 0; j < 4; j++) {
      int col = col0 + wn * 64 + j * 16 + cl;
      float bv = bias[col];
#pragma unroll
      for (int r = 0; r < 4; r++) {
        int row = row0 + wm * 64 + i * 16 + quad * 4 + r;
        out[(size_t)row * 512 + col] = acc[i][j][r] + bv;
      }
    }
  }
}

// ---------------------------------------------------------------------------
extern "C" void kernel_launch(void* const* d_in, const int* in_sizes, int n_in,
                              void* d_out, int out_size, void* d_ws, size_t ws_size,
                              hipStream_t stream) {
  const float* x      = (const float*)d_in[0];
  const float* qkv_w  = (const float*)d_in[1];
  const float* qkv_b  = (const float*)d_in[2];
  const float* proj_w = (const float*)d_in[3];
  const float* proj_b = (const float*)d_in[4];
  const int*   mask   = (const int*)d_in[5];
  float* out = (float*)d_out;

  char* ws = (char*)d_ws;
  bf16* q    = (bf16*)(ws);                 //  [0,  8 MiB)
  bf16* k    = (bf16*)(ws + 8388608);       //  [8, 16 MiB)
  bf16* vt   = (bf16*)(ws + 16777216);      //  [16,24 MiB)
  bf16* attn = (bf16*)(ws + 25165824);      //  [24,32 MiB)  (aliased with xb)
  short* xb  = (short*)(ws + 25165824);     //  xb dead before flash writes attn
  unsigned long long* mbits = (unsigned long long*)(ws + 33554432);  // [32,34 MiB)
  short* wqb = (short*)(ws + 35651584);     //  [34,35.5 MiB)
  short* wpb = (short*)(ws + 37224448);     //  [35.5,36 MiB)

  prep_cvt<<<dim3(1280), 256, 0, stream>>>(x, qkv_w, proj_w, xb, wqb, wpb);
  qkv_union<<<dim3(512 + 768), 256, 0, stream>>>(xb, wqb, qkv_b, mask, mbits, q, k, vt);
  flash_attn<<<dim3(SEQ / 128, NH, NB), 256, 0, stream>>>(q, k, vt, mbits, attn);
  proj_gemm<<<dim3(64, 4), 256, 0, stream>>>(attn, wpb, proj_b, out);
}